// Round 6
// baseline (179.078 us; speedup 1.0000x reference)
//
#include <hip/hip_runtime.h>
#include <hip/hip_bf16.h>

#define Bsz 16
#define Nn  1024
#define Ff  256
#define ALPHA 0.2f
#define LOG2E 1.44269504f

typedef __attribute__((ext_vector_type(8))) short short8;
typedef __attribute__((ext_vector_type(4))) float f32x4;
typedef __attribute__((ext_vector_type(4))) unsigned short ushort4_t;

__device__ __forceinline__ unsigned short f2bf(float x) {
    union { __hip_bfloat16 b; unsigned short u; } cv;
    cv.b = __float2bfloat16(x);
    return cv.u;
}

__device__ __forceinline__ float exp2_fast(float x) {
#if __has_builtin(__builtin_amdgcn_exp2f)
    return __builtin_amdgcn_exp2f(x);
#else
    return exp2f(x);
#endif
}

__device__ __forceinline__ float rcp_fast(float x) {
#if __has_builtin(__builtin_amdgcn_rcpf)
    return __builtin_amdgcn_rcpf(x);
#else
    return 1.f / x;
#endif
}

// ---- K1: pack h -> bf16 K-tiles (hK), W -> WK, fused w1/w2 + f1/f2 --------
// 512 blocks x 1024 thr; block bid packs h-tile bid (32 rows). w1 = W@a1 and
// w2 = W@a2 are recomputed per block (W is L2-resident; 16 float4 per thread)
// which deletes the separate gat_prep dispatch. Blocks 0..15 also pack WK.
__global__ __launch_bounds__(1024, 4) void k_pack(
    const float* __restrict__ h, const float* __restrict__ W,
    const float* __restrict__ a,
    unsigned short* __restrict__ hK, unsigned short* __restrict__ WK,
    float* __restrict__ f1, float* __restrict__ f2)
{
    __shared__ __align__(16) float tile[32][258];
    __shared__ float w1s[Ff], w2s[Ff];
    const int bid = blockIdx.x, t = threadIdx.x, w = t >> 6, ln = t & 63;

    const int grow0 = bid * 32;                       // == (bid>>5)*Nn + (bid&31)*32
    const float* src = h + (size_t)grow0 * Ff;
    const int row = t >> 5, col = (t & 31) * 8;
    const float4 va = *(const float4*)&src[row * Ff + col];
    const float4 vb = *(const float4*)&src[row * Ff + col + 4];

    // w1/w2: thread (f = t>>2, q = t&3) sums a 64-feature quarter of W row f
    {
        const int f = t >> 2, q = t & 3;
        const float4* wr  = (const float4*)(W + (size_t)f * Ff + q * 64);
        const float4* a1p = (const float4*)(a + q * 64);
        const float4* a2p = (const float4*)(a + Ff + q * 64);
        float s1 = 0.f, s2 = 0.f;
        #pragma unroll
        for (int i = 0; i < 16; i++) {
            const float4 wv = wr[i];
            const float4 x1 = a1p[i], x2 = a2p[i];
            s1 += wv.x * x1.x + wv.y * x1.y + wv.z * x1.z + wv.w * x1.w;
            s2 += wv.x * x2.x + wv.y * x2.y + wv.z * x2.z + wv.w * x2.w;
        }
        s1 += __shfl_xor(s1, 1, 64); s1 += __shfl_xor(s1, 2, 64);
        s2 += __shfl_xor(s2, 1, 64); s2 += __shfl_xor(s2, 2, 64);
        if (q == 0) { w1s[f] = s1; w2s[f] = s2; }
    }

    // tile stride 258: rows 8B-aligned -> float2 stores; transpose reads ~2-way (free)
    {
        float2* tr = (float2*)&tile[row][col];
        tr[0] = make_float2(va.x, va.y);
        tr[1] = make_float2(va.z, va.w);
        tr[2] = make_float2(vb.x, vb.y);
        tr[3] = make_float2(vb.z, vb.w);
    }
    __syncthreads();

    // hK pack: word fidx = o*16+q holds rows (2q,2q+1) at feature o
    unsigned* d32 = (unsigned*)(hK + (size_t)bid * 8192);
    #pragma unroll
    for (int k = 0; k < 4; k++) {
        const int fidx = k * 1024 + t;
        const int o = fidx >> 4, q = fidx & 15;
        d32[fidx] = (unsigned)f2bf(tile[2 * q][o]) | ((unsigned)f2bf(tile[2 * q + 1][o]) << 16);
    }
    // f1/f2 for rows 2w, 2w+1 (f1 = h @ w1, f2 = h @ w2)
    #pragma unroll
    for (int rr = 0; rr < 2; rr++) {
        const int r = 2 * w + rr;
        float s1 = 0.f, s2 = 0.f;
        #pragma unroll
        for (int c = 0; c < 4; c++) {
            const int o = ln + 64 * c;
            const float hv = tile[r][o];
            s1 += hv * w1s[o];
            s2 += hv * w2s[o];
        }
        #pragma unroll
        for (int off = 1; off < 64; off <<= 1) {
            s1 += __shfl_xor(s1, off, 64);
            s2 += __shfl_xor(s2, off, 64);
        }
        if (ln == 0) { f1[grow0 + r] = s1; f2[grow0 + r] = s2; }
    }
    // WK: 8 K-tiles of W, half-tile (16 rows) per block for bid<16
    if (bid < 16) {
        const int ft = bid >> 1, half = bid & 1;
        __syncthreads();
        const int r16 = t >> 6, c4 = (t & 63) * 4;
        const float4 wv = *(const float4*)&W[(size_t)(ft * 32 + half * 16 + r16) * Ff + c4];
        float2* tr = (float2*)&tile[r16][c4];
        tr[0] = make_float2(wv.x, wv.y);
        tr[1] = make_float2(wv.z, wv.w);
        __syncthreads();
        unsigned* wd = (unsigned*)(WK + (size_t)ft * 8192);
        #pragma unroll
        for (int k = 0; k < 2; k++) {
            const int j = k * 1024 + t;
            const int o = j >> 3, ql = j & 7;
            wd[o * 16 + half * 8 + ql] =
                (unsigned)f2bf(tile[2 * ql][o]) | ((unsigned)f2bf(tile[2 * ql + 1][o]) << 16);
        }
    }
}

// ---- K2: softmax -> G = P@h (MFMA) -> out = elu(G@W) (MFMA), TI=32 --------
// Round-2-proven structure + 4-deep global B prefetch (hK reads are
// L2-latency-exposed in the MFMA loop; depth 4 covers ~200cy).
__global__ __launch_bounds__(1024, 8) void k_attn(
    const int* __restrict__ adj,
    const float* __restrict__ f1, const float* __restrict__ f2,
    const unsigned short* __restrict__ hK, const unsigned short* __restrict__ WK,
    float* __restrict__ out)
{
    __shared__ __align__(16) unsigned short pbf[32 * 1024];
    __shared__ __align__(16) float ss[32];
    const int t = threadIdx.x, w = t >> 6, ln = t & 63;   // 16 waves
    const int m = ln & 15, quad = ln >> 4;
    const int bid = blockIdx.x;
    const int b2 = 2 * (bid & 7) + ((bid >> 3) & 1);      // XCD-local batches
    const int i0 = (bid >> 4) * 32;

    // ---- Phase A: wave w owns rows 2w, 2w+1 ----
    const int r0 = 2 * w, r1 = r0 + 1;
    const int grb = b2 * Nn + i0 + r0;
    const int* aptr = adj + (size_t)grb * Nn;
    int4 av0[4], av1[4];
    #pragma unroll
    for (int c = 0; c < 4; c++) {
        av0[c] = *(const int4*)&aptr[c * 256 + 4 * ln];
        av1[c] = *(const int4*)&aptr[Nn + c * 256 + 4 * ln];
    }

    float4 f2r[4];
    #pragma unroll
    for (int c = 0; c < 4; c++)
        f2r[c] = *(const float4*)&f2[b2 * Nn + 256 * c + 4 * ln];

    // per-wave max of the f2 row (valid shift: lrelu is monotone)
    float mx2 = fmaxf(fmaxf(f2r[0].x, f2r[0].y), fmaxf(f2r[0].z, f2r[0].w));
    #pragma unroll
    for (int c = 1; c < 4; c++)
        mx2 = fmaxf(mx2, fmaxf(fmaxf(f2r[c].x, f2r[c].y), fmaxf(f2r[c].z, f2r[c].w)));
    #pragma unroll
    for (int off = 1; off < 64; off <<= 1)
        mx2 = fmaxf(mx2, __shfl_xor(mx2, off, 64));

    #pragma unroll
    for (int c = 0; c < 4; c++) {
        f2r[c].x *= LOG2E; f2r[c].y *= LOG2E;
        f2r[c].z *= LOG2E; f2r[c].w *= LOG2E;
    }

    const float fi0 = f1[grb], fi1 = f1[grb + 1];
    float q0 = fi0 + mx2; q0 = fmaxf(q0, ALPHA * q0);
    float q1 = fi1 + mx2; q1 = fmaxf(q1, ALPHA * q1);
    const float mx0L = q0 * LOG2E, mx1L = q1 * LOG2E;
    const float fi0L = fi0 * LOG2E, fi1L = fi1 * LOG2E;
    const int sw0 = (r0 & 7) << 3, sw1 = (r1 & 7) << 3;

    float s0 = 0.f, s1 = 0.f;
    #pragma unroll
    for (int c = 0; c < 4; c++) {
        const float4 fv = f2r[c];
        float x, p00, p01, p02, p03, p10, p11, p12, p13;
        x = fi0L + fv.x; x = fmaxf(x, ALPHA * x); p00 = av0[c].x > 0 ? exp2_fast(x - mx0L) : 0.f;
        x = fi0L + fv.y; x = fmaxf(x, ALPHA * x); p01 = av0[c].y > 0 ? exp2_fast(x - mx0L) : 0.f;
        x = fi0L + fv.z; x = fmaxf(x, ALPHA * x); p02 = av0[c].z > 0 ? exp2_fast(x - mx0L) : 0.f;
        x = fi0L + fv.w; x = fmaxf(x, ALPHA * x); p03 = av0[c].w > 0 ? exp2_fast(x - mx0L) : 0.f;
        x = fi1L + fv.x; x = fmaxf(x, ALPHA * x); p10 = av1[c].x > 0 ? exp2_fast(x - mx1L) : 0.f;
        x = fi1L + fv.y; x = fmaxf(x, ALPHA * x); p11 = av1[c].y > 0 ? exp2_fast(x - mx1L) : 0.f;
        x = fi1L + fv.z; x = fmaxf(x, ALPHA * x); p12 = av1[c].z > 0 ? exp2_fast(x - mx1L) : 0.f;
        x = fi1L + fv.w; x = fmaxf(x, ALPHA * x); p13 = av1[c].w > 0 ? exp2_fast(x - mx1L) : 0.f;
        s0 += (p00 + p01) + (p02 + p03);
        s1 += (p10 + p11) + (p12 + p13);
        const int j = 256 * c + 4 * ln;
        ushort4_t v0 = { f2bf(p00), f2bf(p01), f2bf(p02), f2bf(p03) };
        ushort4_t v1 = { f2bf(p10), f2bf(p11), f2bf(p12), f2bf(p13) };
        *(ushort4_t*)&pbf[r0 * 1024 + (j ^ sw0)] = v0;
        *(ushort4_t*)&pbf[r1 * 1024 + (j ^ sw1)] = v1;
    }
    #pragma unroll
    for (int off = 1; off < 64; off <<= 1) {
        s0 += __shfl_xor(s0, off, 64);
        s1 += __shfl_xor(s1, off, 64);
    }
    if (ln == 0) { ss[r0] = s0; ss[r1] = s1; }

    // ---- Phase B: G = softmax(P) @ h_b ; wave n-slice 16, both m-halves ----
    const int n0 = w * 16;
    const unsigned short* hKb = hK + (size_t)b2 * 32 * 8192;
    const int arow0 = m * 1024, arow1 = (16 + m) * 1024;
    const int asw = (m & 7) << 3;
    #define AF0(kt) (*(const short8*)&pbf[arow0 + ((((kt) * 32) + quad * 8) ^ asw)])
    #define AF1(kt) (*(const short8*)&pbf[arow1 + ((((kt) * 32) + quad * 8) ^ asw)])
    #define BF(kt)  (*(const short8*)&hKb[(size_t)(kt) * 8192 + (n0 + m) * 32 + quad * 8])

    // 4-deep global B prefetch (no pbf dependency) before the barrier
    short8 bq0 = BF(0), bq1 = BF(1), bq2 = BF(2), bq3 = BF(3);
    __syncthreads();

    f32x4 acc0 = {0.f, 0.f, 0.f, 0.f}, acc1 = acc0;
    short8 a0c = AF0(0), a1c = AF1(0);
    __builtin_amdgcn_s_setprio(1);
    #pragma unroll
    for (int kt = 0; kt < 32; kt++) {
        short8 bnew = bq0, a0n = a0c, a1n = a1c;
        if (kt + 4 < 32) bnew = BF(kt + 4);
        if (kt + 1 < 32) { a0n = AF0(kt + 1); a1n = AF1(kt + 1); }
        acc0 = __builtin_amdgcn_mfma_f32_16x16x32_bf16(a0c, bq0, acc0, 0, 0, 0);
        acc1 = __builtin_amdgcn_mfma_f32_16x16x32_bf16(a1c, bq0, acc1, 0, 0, 0);
        a0c = a0n; a1c = a1n;
        bq0 = bq1; bq1 = bq2; bq2 = bq3; bq3 = bnew;
    }
    __builtin_amdgcn_s_setprio(0);

    // normalize rows by 1/s (C row = quad*4+reg aligns with ss layout)
    const f32x4 sv0 = *(const f32x4*)&ss[quad * 4];
    const f32x4 sv1 = *(const f32x4*)&ss[16 + quad * 4];

    __syncthreads();   // P dead; reuse pbf for G (stride 264)
    #pragma unroll
    for (int reg = 0; reg < 4; reg++) {
        const float i0s = rcp_fast(fmaxf(sv0[reg], 1e-30f));
        const float i1s = rcp_fast(fmaxf(sv1[reg], 1e-30f));
        pbf[(quad * 4 + reg) * 264 + n0 + m]      = f2bf(acc0[reg] * i0s);
        pbf[(16 + quad * 4 + reg) * 264 + n0 + m] = f2bf(acc1[reg] * i1s);
    }

    // ---- Phase C: out = elu( G @ W ) ; same wave mapping ----
    #define GA0(kt) (*(const short8*)&pbf[m * 264 + (kt) * 32 + quad * 8])
    #define GA1(kt) (*(const short8*)&pbf[(16 + m) * 264 + (kt) * 32 + quad * 8])
    #define WB(kt)  (*(const short8*)&WK[(size_t)(kt) * 8192 + (n0 + m) * 32 + quad * 8])

    short8 wbc = WB(0), wbn = WB(1);   // global prefetch across the barrier
    __syncthreads();

    f32x4 c0 = {0.f, 0.f, 0.f, 0.f}, c1 = c0;
    short8 ga0 = GA0(0), ga1 = GA1(0);
    __builtin_amdgcn_s_setprio(1);
    #pragma unroll
    for (int kt = 0; kt < 8; kt++) {
        short8 ga0n = ga0, ga1n = ga1, wnew = wbc;
        if (kt + 2 < 8) wnew = WB(kt + 2);
        if (kt + 1 < 8) { ga0n = GA0(kt + 1); ga1n = GA1(kt + 1); }
        c0 = __builtin_amdgcn_mfma_f32_16x16x32_bf16(ga0, wbc, c0, 0, 0, 0);
        c1 = __builtin_amdgcn_mfma_f32_16x16x32_bf16(ga1, wbc, c1, 0, 0, 0);
        ga0 = ga0n; ga1 = ga1n; wbc = wbn; wbn = wnew;
    }
    __builtin_amdgcn_s_setprio(0);
    const size_t ob = (size_t)(b2 * Nn) + i0;
    #pragma unroll
    for (int reg = 0; reg < 4; reg++) {
        float v;
        v = c0[reg]; v = v > 0.f ? v : (__expf(v) - 1.f);
        out[(ob + quad * 4 + reg) * Ff + n0 + m] = v;
        v = c1[reg]; v = v > 0.f ? v : (__expf(v) - 1.f);
        out[(ob + 16 + quad * 4 + reg) * Ff + n0 + m] = v;
    }
}

extern "C" void kernel_launch(void* const* d_in, const int* in_sizes, int n_in,
                              void* d_out, int out_size, void* d_ws, size_t ws_size,
                              hipStream_t stream)
{
    const void* h   = d_in[0];
    const void* adj = d_in[1];
    const void* W   = d_in[2];
    const void* a   = d_in[3];
    for (int i = 0; i < n_in; i++) {
        if      (in_sizes[i] == Bsz * Nn * Ff) h   = d_in[i];
        else if (in_sizes[i] == Bsz * Nn * Nn) adj = d_in[i];
        else if (in_sizes[i] == Ff * Ff)       W   = d_in[i];
        else if (in_sizes[i] == 2 * Ff)        a   = d_in[i];
    }
    char* wsb = (char*)d_ws;
    float* f1 = (float*)wsb;                                     // 64 KiB
    float* f2 = (float*)(wsb + 65536);                           // 64 KiB
    unsigned short* hK = (unsigned short*)(wsb + 2 * 65536);     // 8 MiB
    unsigned short* WK = hK + (size_t)Bsz * 32 * 8192;           // 128 KiB

    k_pack<<<512, 1024, 0, stream>>>((const float*)h, (const float*)W,
                                     (const float*)a, hK, WK, f1, f2);
    k_attn<<<512, 1024, 0, stream>>>((const int*)adj, f1, f2, hK, WK,
                                     (float*)d_out);
}

// Round 7
// 138.659 us; speedup vs baseline: 1.2915x; 1.2915x over previous
//
#include <hip/hip_runtime.h>
#include <hip/hip_bf16.h>

#define Bsz 16
#define Nn  1024
#define Ff  256
#define ALPHA 0.2f
#define NEG_BIG -9.0e15f

typedef __attribute__((ext_vector_type(8))) short short8;
typedef __attribute__((ext_vector_type(4))) float f32x4;
typedef __attribute__((ext_vector_type(4))) unsigned short ushort4_t;

__device__ __forceinline__ unsigned short f2bf(float x) {
    union { __hip_bfloat16 b; unsigned short u; } cv;
    cv.b = __float2bfloat16(x);
    return cv.u;
}

// ---- K0: w1 = W@a1 ; w2 = W@a2  (64 blocks, wave per output f) ------------
__global__ __launch_bounds__(256) void gat_prep(
    const float* __restrict__ W, const float* __restrict__ a,
    float* __restrict__ w1, float* __restrict__ w2)
{
    const int t = threadIdx.x, w = t >> 6, ln = t & 63;
    __shared__ float a1s[Ff], a2s[Ff];
    a1s[t] = a[t];
    a2s[t] = a[Ff + t];
    __syncthreads();
    const int f = blockIdx.x * 4 + w;
    float s1 = 0.f, s2 = 0.f;
    #pragma unroll
    for (int c = 0; c < 4; c++) {
        const int o = ln + 64 * c;
        const float wv = W[(size_t)f * Ff + o];
        s1 += wv * a1s[o];
        s2 += wv * a2s[o];
    }
    #pragma unroll
    for (int off = 1; off < 64; off <<= 1) {
        s1 += __shfl_xor(s1, off, 64);
        s2 += __shfl_xor(s2, off, 64);
    }
    if (ln == 0) { w1[f] = s1; w2[f] = s2; }
}

// ---- K1: pack/transpose h,W to bf16 K-tiles + fused f1/f2 -----------------
// tile stride 258 floats: transpose-read banks (4q+o)%32 -> 2-way (free, was
// 4-way at stride 260); rows 8B-aligned -> float2 stores, conflict-free.
__global__ __launch_bounds__(256) void pack_f(
    const float* __restrict__ h, const float* __restrict__ W,
    const float* __restrict__ w1, const float* __restrict__ w2,
    unsigned short* __restrict__ hK, unsigned short* __restrict__ WK,
    float* __restrict__ f1, float* __restrict__ f2)
{
    __shared__ __align__(16) float tile[32][258];
    const int id = blockIdx.x, t = threadIdx.x, w = t >> 6, ln = t & 63;
    const bool isH = (id < 512);
    const float* src;
    unsigned short* dst;
    int grow0 = 0;
    if (isH) {
        const int b = id >> 5, kt = id & 31;
        grow0 = b * Nn + kt * 32;
        src = h + (size_t)grow0 * Ff;
        dst = hK + ((size_t)(b * 32 + kt)) * 8192;
    } else {
        const int ft = id - 512;
        src = W + (size_t)ft * 32 * Ff;
        dst = WK + (size_t)ft * 8192;
    }
    #pragma unroll
    for (int rr = 0; rr < 8; rr++) {
        const int row = rr * 4 + w;
        const int col = ln * 4;
        const float4 v = *(const float4*)&src[row * Ff + col];
        float2* tr = (float2*)&tile[row][col];
        tr[0] = make_float2(v.x, v.y);
        tr[1] = make_float2(v.z, v.w);
    }
    __syncthreads();

    unsigned* d32 = (unsigned*)dst;
    #pragma unroll
    for (int k = 0; k < 16; k++) {
        const int fidx = k * 256 + t;
        const int o = fidx >> 4, q = fidx & 15;
        const unsigned lo = f2bf(tile[2 * q][o]);
        const unsigned hi = f2bf(tile[2 * q + 1][o]);
        d32[fidx] = lo | (hi << 16);
    }

    if (isH) {
        float w1r[4], w2r[4];
        #pragma unroll
        for (int c = 0; c < 4; c++) {
            w1r[c] = w1[ln + 64 * c];
            w2r[c] = w2[ln + 64 * c];
        }
        #pragma unroll
        for (int rr = 0; rr < 8; rr++) {
            const int row = rr * 4 + w;
            float s1 = 0.f, s2 = 0.f;
            #pragma unroll
            for (int c = 0; c < 4; c++) {
                const float hv = tile[row][ln + 64 * c];
                s1 += hv * w1r[c];
                s2 += hv * w2r[c];
            }
            #pragma unroll
            for (int off = 1; off < 64; off <<= 1) {
                s1 += __shfl_xor(s1, off, 64);
                s2 += __shfl_xor(s2, off, 64);
            }
            if (ln == 0) { f1[grow0 + row] = s1; f2[grow0 + row] = s2; }
        }
    }
}

// ---- K2: softmax -> G = P@h (MFMA) -> out = elu(G@W) (MFMA), TI=32 --------
// Round-1 structure (measured best) + (a) 4-deep BF global prefetch issued
// BEFORE the phase-A barrier (barrier's vmcnt drain completes them; MFMA loop
// starts with hot B-frags), (b) WB prefetch hoisted above the G-write
// barriers, (c) setprio(1) around both MFMA loops.
#define TI 32
__global__ __launch_bounds__(1024, 8) void gat_attn(
    const int* __restrict__ adj,
    const float* __restrict__ f1, const float* __restrict__ f2,
    const unsigned short* __restrict__ hK, const unsigned short* __restrict__ WK,
    float* __restrict__ out)
{
    // 64 KB: P (swizzled, stride 1024) in phases A/B; G (stride 264) in C
    __shared__ __align__(16) unsigned short pbf[TI * 1024];
    const int t = threadIdx.x, w = t >> 6, ln = t & 63;   // 16 waves
    const int m = ln & 15, quad = ln >> 4;
    const int bid = blockIdx.x;
    const int b  = 2 * (bid & 7) + ((bid >> 3) & 1);      // XCD-local batches
    const int i0 = (bid >> 4) * TI;

    // ---- Phase A: wave w owns rows 2w, 2w+1 ----
    const int r0 = 2 * w, r1 = r0 + 1;
    const int grb = b * Nn + i0 + r0;
    const int* aptr = adj + (size_t)grb * Nn;
    int4 av0[4], av1[4];
    #pragma unroll
    for (int c = 0; c < 4; c++) {
        av0[c] = *(const int4*)&aptr[c * 256 + 4 * ln];
        av1[c] = *(const int4*)&aptr[Nn + c * 256 + 4 * ln];
    }
    float4 f2r[4];
    #pragma unroll
    for (int c = 0; c < 4; c++)
        f2r[c] = *(const float4*)&f2[b * Nn + 256 * c + 4 * ln];

    const float fi0 = f1[grb], fi1 = f1[grb + 1];
    float e0[16], e1[16];
    float mx0 = -INFINITY, mx1 = -INFINITY;
    #pragma unroll
    for (int c = 0; c < 4; c++) {
        const float4 fv = f2r[c];
        float x, y;
        x = fi0 + fv.x; x = fmaxf(x, ALPHA * x); x = av0[c].x > 0 ? x : NEG_BIG; e0[4*c+0] = x;
        y = fi0 + fv.y; y = fmaxf(y, ALPHA * y); y = av0[c].y > 0 ? y : NEG_BIG; e0[4*c+1] = y;
        mx0 = fmaxf(fmaxf(x, y), mx0);
        x = fi0 + fv.z; x = fmaxf(x, ALPHA * x); x = av0[c].z > 0 ? x : NEG_BIG; e0[4*c+2] = x;
        y = fi0 + fv.w; y = fmaxf(y, ALPHA * y); y = av0[c].w > 0 ? y : NEG_BIG; e0[4*c+3] = y;
        mx0 = fmaxf(fmaxf(x, y), mx0);
        x = fi1 + fv.x; x = fmaxf(x, ALPHA * x); x = av1[c].x > 0 ? x : NEG_BIG; e1[4*c+0] = x;
        y = fi1 + fv.y; y = fmaxf(y, ALPHA * y); y = av1[c].y > 0 ? y : NEG_BIG; e1[4*c+1] = y;
        mx1 = fmaxf(fmaxf(x, y), mx1);
        x = fi1 + fv.z; x = fmaxf(x, ALPHA * x); x = av1[c].z > 0 ? x : NEG_BIG; e1[4*c+2] = x;
        y = fi1 + fv.w; y = fmaxf(y, ALPHA * y); y = av1[c].w > 0 ? y : NEG_BIG; e1[4*c+3] = y;
        mx1 = fmaxf(fmaxf(x, y), mx1);
    }
    #pragma unroll
    for (int off = 1; off < 64; off <<= 1) {
        mx0 = fmaxf(mx0, __shfl_xor(mx0, off, 64));
        mx1 = fmaxf(mx1, __shfl_xor(mx1, off, 64));
    }
    float s0 = 0.f, s1 = 0.f;
    #pragma unroll
    for (int c = 0; c < 16; c++) {
        e0[c] = __expf(e0[c] - mx0); s0 += e0[c];   // all-masked row -> uniform
        e1[c] = __expf(e1[c] - mx1); s1 += e1[c];
    }
    #pragma unroll
    for (int off = 1; off < 64; off <<= 1) {
        s0 += __shfl_xor(s0, off, 64);
        s1 += __shfl_xor(s1, off, 64);
    }
    const float ri0 = 1.f / s0, ri1 = 1.f / s1;
    const int sw0 = (r0 & 7) << 3, sw1 = (r1 & 7) << 3;
    #pragma unroll
    for (int c = 0; c < 4; c++) {
        const int j = 256 * c + 4 * ln;
        ushort4_t v0 = { f2bf(e0[4*c] * ri0), f2bf(e0[4*c+1] * ri0),
                         f2bf(e0[4*c+2] * ri0), f2bf(e0[4*c+3] * ri0) };
        ushort4_t v1 = { f2bf(e1[4*c] * ri1), f2bf(e1[4*c+1] * ri1),
                         f2bf(e1[4*c+2] * ri1), f2bf(e1[4*c+3] * ri1) };
        *(ushort4_t*)&pbf[r0 * 1024 + (j ^ sw0)] = v0;
        *(ushort4_t*)&pbf[r1 * 1024 + (j ^ sw1)] = v1;
    }

    // ---- Phase B: G = P @ h_b ; wave n-slice 16, both m-halves ----
    const int n0 = w * 16;
    const unsigned short* hKb = hK + (size_t)b * 32 * 8192;
    const int arow0 = m * 1024, arow1 = (16 + m) * 1024;
    const int asw = (m & 7) << 3;
    #define AF0(kt) (*(const short8*)&pbf[arow0 + ((((kt) * 32) + quad * 8) ^ asw)])
    #define AF1(kt) (*(const short8*)&pbf[arow1 + ((((kt) * 32) + quad * 8) ^ asw)])
    #define BF(kt)  (*(const short8*)&hKb[(size_t)(kt) * 8192 + (n0 + m) * 32 + quad * 8])

    // 4-deep global prefetch, no pbf dependency -> issue BEFORE barrier
    short8 bq0 = BF(0), bq1 = BF(1), bq2 = BF(2), bq3 = BF(3);
    __syncthreads();

    f32x4 acc0 = {0.f, 0.f, 0.f, 0.f}, acc1 = acc0;
    short8 a0c = AF0(0), a1c = AF1(0);
    __builtin_amdgcn_s_setprio(1);
    #pragma unroll
    for (int kt = 0; kt < 32; kt++) {
        short8 bnew = bq0, a0n = a0c, a1n = a1c;
        if (kt + 4 < 32) bnew = BF(kt + 4);
        if (kt + 1 < 32) { a0n = AF0(kt + 1); a1n = AF1(kt + 1); }
        acc0 = __builtin_amdgcn_mfma_f32_16x16x32_bf16(a0c, bq0, acc0, 0, 0, 0);
        acc1 = __builtin_amdgcn_mfma_f32_16x16x32_bf16(a1c, bq0, acc1, 0, 0, 0);
        a0c = a0n; a1c = a1n;
        bq0 = bq1; bq1 = bq2; bq2 = bq3; bq3 = bnew;
    }
    __builtin_amdgcn_s_setprio(0);

    // WB prefetch (global, no LDS dep) hoisted above the G-write barriers
    #define WB(kt)  (*(const short8*)&WK[(size_t)(kt) * 8192 + (n0 + m) * 32 + quad * 8])
    short8 wbc = WB(0), wbn = WB(1);

    __syncthreads();   // P dead; reuse pbf for G (stride 264)
    #pragma unroll
    for (int reg = 0; reg < 4; reg++) {
        pbf[(quad * 4 + reg) * 264 + n0 + m]      = f2bf(acc0[reg]);
        pbf[(16 + quad * 4 + reg) * 264 + n0 + m] = f2bf(acc1[reg]);
    }
    __syncthreads();

    // ---- Phase C: out = elu( G @ W ) ; same wave mapping ----
    #define GA0(kt) (*(const short8*)&pbf[m * 264 + (kt) * 32 + quad * 8])
    #define GA1(kt) (*(const short8*)&pbf[(16 + m) * 264 + (kt) * 32 + quad * 8])

    f32x4 c0 = {0.f, 0.f, 0.f, 0.f}, c1 = c0;
    short8 ga0 = GA0(0), ga1 = GA1(0);
    __builtin_amdgcn_s_setprio(1);
    #pragma unroll
    for (int kt = 0; kt < 8; kt++) {
        short8 ga0n = ga0, ga1n = ga1, wnew = wbc;
        if (kt + 2 < 8) wnew = WB(kt + 2);
        if (kt + 1 < 8) { ga0n = GA0(kt + 1); ga1n = GA1(kt + 1); }
        c0 = __builtin_amdgcn_mfma_f32_16x16x32_bf16(ga0, wbc, c0, 0, 0, 0);
        c1 = __builtin_amdgcn_mfma_f32_16x16x32_bf16(ga1, wbc, c1, 0, 0, 0);
        ga0 = ga0n; ga1 = ga1n; wbc = wbn; wbn = wnew;
    }
    __builtin_amdgcn_s_setprio(0);
    const size_t ob = (size_t)(b * Nn) + i0;
    #pragma unroll
    for (int reg = 0; reg < 4; reg++) {
        float v;
        v = c0[reg]; v = v > 0.f ? v : (__expf(v) - 1.f);
        out[(ob + quad * 4 + reg) * Ff + n0 + m] = v;
        v = c1[reg]; v = v > 0.f ? v : (__expf(v) - 1.f);
        out[(ob + 16 + quad * 4 + reg) * Ff + n0 + m] = v;
    }
}

extern "C" void kernel_launch(void* const* d_in, const int* in_sizes, int n_in,
                              void* d_out, int out_size, void* d_ws, size_t ws_size,
                              hipStream_t stream)
{
    const void* h   = d_in[0];
    const void* adj = d_in[1];
    const void* W   = d_in[2];
    const void* a   = d_in[3];
    for (int i = 0; i < n_in; i++) {
        if      (in_sizes[i] == Bsz * Nn * Ff) h   = d_in[i];
        else if (in_sizes[i] == Bsz * Nn * Nn) adj = d_in[i];
        else if (in_sizes[i] == Ff * Ff)       W   = d_in[i];
        else if (in_sizes[i] == 2 * Ff)        a   = d_in[i];
    }
    float* out = (float*)d_out;

    char*  wsb = (char*)d_ws;
    float* w1  = (float*)wsb;                                   // 1 KiB
    float* w2  = w1 + Ff;                                       // 1 KiB
    float* f1  = (float*)(wsb + 4096);                          // 64 KiB
    float* f2  = f1 + Bsz * Nn;                                 // 64 KiB
    unsigned short* hK = (unsigned short*)(wsb + 4096 + 2 * 65536);  // 8 MiB
    unsigned short* WK = hK + (size_t)Bsz * 32 * 8192;               // 128 KiB

    gat_prep<<<64, 256, 0, stream>>>((const float*)W, (const float*)a, w1, w2);
    pack_f<<<520, 256, 0, stream>>>((const float*)h, (const float*)W, w1, w2, hK, WK, f1, f2);
    gat_attn<<<Bsz * (Nn / TI), 1024, 0, stream>>>((const int*)adj, f1, f2, hK, WK, out);
}